// Round 16
// baseline (387.618 us; speedup 1.0000x reference)
//
#include <hip/hip_runtime.h>
#include <hip/hip_bf16.h>
#include <cstdint>

#define CDIM 256
#define KNN  16
#define NCQ  128    // Q chunks:  grid 4*128 = 512 blocks (2/CU, 32 waves/CU)
#define NCKV 64     // KV chunks: grid 4*64  = 256 blocks (1/CU, 16 waves/CU)

typedef __attribute__((ext_vector_type(8))) __bf16 bf16x8;
typedef __attribute__((ext_vector_type(4))) float  f4;
typedef __attribute__((ext_vector_type(4))) unsigned short u16x4;

__device__ inline ushort f2bf(float f) {
    __bf16 b = (__bf16)f;
    return __builtin_bit_cast(ushort, b);
}
__device__ inline float bf2f(ushort h) {
    return __builtin_bit_cast(float, (unsigned int)h << 16);
}
__device__ inline bf16x8 cvt8(f4 a, f4 b) {
    bf16x8 r;
    r[0] = (__bf16)a[0]; r[1] = (__bf16)a[1]; r[2] = (__bf16)a[2]; r[3] = (__bf16)a[3];
    r[4] = (__bf16)b[0]; r[5] = (__bf16)b[1]; r[6] = (__bf16)b[2]; r[7] = (__bf16)b[3];
    return r;
}
__device__ inline ushort4 packbf(f4 v) {
    ushort4 h;
    h.x = f2bf(v[0]); h.y = f2bf(v[1]); h.z = f2bf(v[2]); h.w = f2bf(v[3]);
    return h;
}

// stage a 64-row x 256-col f32 weight slice -> bf16 LDS, XOR-swizzled.
__device__ inline void stage_w(const float* Wm, int wbase, ushort* dst, int tid) {
    #pragma unroll
    for (int i = 0; i < 4; i++) {
        int idx = i * 1024 + tid;
        int row = idx >> 6, c4 = idx & 63;
        float4 v = *(const float4*)(Wm + (size_t)(wbase + row) * CDIM + c4 * 4);
        ushort4 h;
        h.x = f2bf(v.x); h.y = f2bf(v.y); h.z = f2bf(v.z); h.w = f2bf(v.w);
        *(ushort4*)((char*)dst + row * 512 + ((c4 * 8) ^ ((row & 7) << 4))) = h;
    }
}

// Q projection: 16-wave blocks, one 32 KB Wq slice, 2 blocks/CU (r12-proven).
__global__ __launch_bounds__(1024, 4)
void proj_q(const float* __restrict__ qf, const float* __restrict__ Wq,
            const float* __restrict__ bq, ushort* __restrict__ Qout,
            int M, int nwg, int ngroups)
{
    __shared__ ushort Wlds[64 * CDIM];   // 32 KB

    const int orig = blockIdx.x;
    const int xcd = orig & 7, lin = orig >> 3;
    const int wgid = xcd * (nwg >> 3) + lin;       // nwg % 8 == 0
    const int chunk = wgid >> 2, ws = wgid & 3;

    const int tid  = threadIdx.x;
    const int lane = tid & 63;
    const int wid  = tid >> 6;                     // 0..15
    const int l15  = lane & 15, l4 = lane >> 4;
    const int wbase = ws * 64;

    stage_w(Wq, wbase, Wlds, tid);
    __syncthreads();

    f4 biasf[4];
    #pragma unroll
    for (int mi = 0; mi < 4; mi++)
        biasf[mi] = *(const f4*)(bq + wbase + mi * 16 + l4 * 4);

    for (int g = chunk; g < ngroups; g += NCQ) {
        const int m0 = g * 256 + wid * 16;
        if (m0 >= M) continue;                     // M % 16 == 0
        const float* fp = qf + (size_t)m0 * CDIM + (size_t)l15 * CDIM + l4 * 8;

        f4 rawA[8], rawB[8];
        #pragma unroll
        for (int ks = 0; ks < 8; ks++) {
            rawA[ks] = *(const f4*)(fp + ks * 32);
            rawB[ks] = *(const f4*)(fp + ks * 32 + 4);
        }
        __builtin_amdgcn_sched_barrier(0);

        f4 acc[4];
        #pragma unroll
        for (int mi = 0; mi < 4; mi++) acc[mi] = (f4){0.f, 0.f, 0.f, 0.f};
        #pragma unroll
        for (int ks = 0; ks < 8; ks++) {
            const bf16x8 af = cvt8(rawA[ks], rawB[ks]);
            #pragma unroll
            for (int mi = 0; mi < 4; mi++) {
                const int r = mi * 16 + l15;
                const bf16x8 wfr = *(const bf16x8*)((const char*)Wlds + r * 512
                                      + ((ks * 64 + l4 * 16) ^ ((r & 7) << 4)));
                acc[mi] = __builtin_amdgcn_mfma_f32_16x16x32_bf16(wfr, af, acc[mi], 0, 0, 0);
            }
        }

        const int m = m0 + l15;
        #pragma unroll
        for (int mi = 0; mi < 4; mi++) {
            const int wr0 = wbase + mi * 16 + l4 * 4;
            *(ushort4*)(Qout + (size_t)m * CDIM + wr0) = packbf(acc[mi] + biasf[mi]);
        }
    }
}

// K+V projection: 16-wave blocks, dual 64 KB Wk/Wv slices (r12-proven).
// Writes SEPARATE Kt / Vt arrays for the phase-split attn.
__global__ __launch_bounds__(1024, 4)
void proj_kv(const float* __restrict__ kvf,
             const float* __restrict__ Wk, const float* __restrict__ Wv,
             const float* __restrict__ bk, const float* __restrict__ bv,
             const float* __restrict__ sens,
             ushort* __restrict__ Kt, ushort* __restrict__ Vt,
             int M, int Npts, int nwg, int ngroups)
{
    __shared__ ushort Wlds[2][64 * CDIM];   // 64 KB

    const int orig = blockIdx.x;
    const int xcd = orig & 7, lin = orig >> 3;
    const int wgid = xcd * (nwg >> 3) + lin;
    const int chunk = wgid >> 2, ws = wgid & 3;

    const int tid  = threadIdx.x;
    const int lane = tid & 63;
    const int wid  = tid >> 6;
    const int l15  = lane & 15, l4 = lane >> 4;
    const int wbase = ws * 64;

    stage_w(Wk, wbase, &Wlds[0][0], tid);
    stage_w(Wv, wbase, &Wlds[1][0], tid);
    __syncthreads();

    f4 biasK[4], biasV[4];
    #pragma unroll
    for (int mi = 0; mi < 4; mi++) {
        biasK[mi] = *(const f4*)(bk + wbase + mi * 16 + l4 * 4);
        biasV[mi] = *(const f4*)(bv + wbase + mi * 16 + l4 * 4);
    }

    for (int g = chunk; g < ngroups; g += NCKV) {
        const int m0 = g * 256 + wid * 16;
        if (m0 >= M) continue;
        const float* fp = kvf + (size_t)m0 * CDIM + (size_t)l15 * CDIM + l4 * 8;

        f4 rawA[8], rawB[8];
        #pragma unroll
        for (int ks = 0; ks < 8; ks++) {
            rawA[ks] = *(const f4*)(fp + ks * 32);
            rawB[ks] = *(const f4*)(fp + ks * 32 + 4);
        }
        __builtin_amdgcn_sched_barrier(0);

        f4 accK[4], accV[4];
        #pragma unroll
        for (int mi = 0; mi < 4; mi++) {
            accK[mi] = (f4){0.f, 0.f, 0.f, 0.f};
            accV[mi] = (f4){0.f, 0.f, 0.f, 0.f};
        }
        #pragma unroll
        for (int ks = 0; ks < 8; ks++) {
            const bf16x8 af = cvt8(rawA[ks], rawB[ks]);
            #pragma unroll
            for (int mi = 0; mi < 4; mi++) {
                const int r = mi * 16 + l15;
                const int cb = (ks * 64 + l4 * 16) ^ ((r & 7) << 4);
                const bf16x8 wk = *(const bf16x8*)((const char*)&Wlds[0][0] + r * 512 + cb);
                accK[mi] = __builtin_amdgcn_mfma_f32_16x16x32_bf16(wk, af, accK[mi], 0, 0, 0);
                const bf16x8 wv = *(const bf16x8*)((const char*)&Wlds[1][0] + r * 512 + cb);
                accV[mi] = __builtin_amdgcn_mfma_f32_16x16x32_bf16(wv, af, accV[mi], 0, 0, 0);
            }
        }

        const int m = m0 + l15;
        const int nidx = m >= Npts ? m - Npts : m;
        const float sw = sens[nidx];
        #pragma unroll
        for (int mi = 0; mi < 4; mi++) {
            const int wr0 = wbase + mi * 16 + l4 * 4;
            *(ushort4*)(Kt + (size_t)m * CDIM + wr0) = packbf((accK[mi] + biasK[mi]) * sw);
            *(ushort4*)(Vt + (size_t)m * CDIM + wr0) = packbf((accV[mi] + biasV[mi]) * sw);
        }
    }
}

// Phase A: per point gather 16 K rows, dot, softmax -> 16 probs.
// Q / probs streams nontemporal: keep L3 for the K gather set.
__global__ __launch_bounds__(256, 4)
void attn_score(const ushort* __restrict__ Qb, const ushort* __restrict__ Kt,
                const int* __restrict__ knn, float* __restrict__ probs, int Npts)
{
    const int gi = blockIdx.x * 4 + (threadIdx.x >> 6);   // [0, 2*Npts)
    const int lane = threadIdx.x & 63;
    const int base = gi >= Npts ? Npts : 0;
    const int n    = gi - base;
    if (n >= Npts) return;

    const u16x4 qh = __builtin_nontemporal_load(
        (const u16x4*)(Qb + (size_t)gi * CDIM + lane * 4));

    const int ns = __builtin_amdgcn_readfirstlane(n);
    const int* ki = knn + ns * KNN;
    int idxs[KNN];
    #pragma unroll
    for (int j = 0; j < KNN; j++) idxs[j] = ki[j];

    ushort4 kr[KNN];
    #pragma unroll
    for (int j = 0; j < KNN; j++)
        kr[j] = *(const ushort4*)(Kt + (size_t)(base + idxs[j]) * CDIM + lane * 4);
    __builtin_amdgcn_sched_barrier(0);

    f4 q;
    q[0] = bf2f(qh[0]); q[1] = bf2f(qh[1]); q[2] = bf2f(qh[2]); q[3] = bf2f(qh[3]);

    float d[KNN];
    #pragma unroll
    for (int j = 0; j < KNN; j++)
        d[j] = q[0] * bf2f(kr[j].x) + q[1] * bf2f(kr[j].y)
             + q[2] * bf2f(kr[j].z) + q[3] * bf2f(kr[j].w);

    #pragma unroll
    for (int m = 1; m < 64; m <<= 1) {
        #pragma unroll
        for (int j = 0; j < KNN; j++) d[j] += __shfl_xor(d[j], m, 64);
    }

    float mx = -1e30f;
    #pragma unroll
    for (int j = 0; j < KNN; j++) { d[j] *= 0.0625f; mx = fmaxf(mx, d[j]); }
    float s = 0.f;
    #pragma unroll
    for (int j = 0; j < KNN; j++) { d[j] = __expf(d[j] - mx); s += d[j]; }
    const float inv = 1.f / s;

    if (lane == 0) {
        float* pp = probs + (size_t)gi * KNN;
        __builtin_nontemporal_store(
            (f4){d[0] * inv, d[1] * inv, d[2] * inv, d[3] * inv}, (f4*)pp);
        __builtin_nontemporal_store(
            (f4){d[4] * inv, d[5] * inv, d[6] * inv, d[7] * inv}, (f4*)(pp + 4));
        __builtin_nontemporal_store(
            (f4){d[8] * inv, d[9] * inv, d[10] * inv, d[11] * inv}, (f4*)(pp + 8));
        __builtin_nontemporal_store(
            (f4){d[12] * inv, d[13] * inv, d[14] * inv, d[15] * inv}, (f4*)(pp + 12));
    }
}

// Phase B: per point gather 16 V rows, weighted sum, residual + LayerNorm.
__global__ __launch_bounds__(256, 4)
void attn_pv(const ushort* __restrict__ Qb, const ushort* __restrict__ Vt,
             const int* __restrict__ knn, const float* __restrict__ probs,
             float* __restrict__ Out,
             const float* __restrict__ ln_g, const float* __restrict__ ln_b,
             int Npts)
{
    const int gi = blockIdx.x * 4 + (threadIdx.x >> 6);
    const int lane = threadIdx.x & 63;
    const int base = gi >= Npts ? Npts : 0;
    const int n    = gi - base;
    if (n >= Npts) return;

    const int ns = __builtin_amdgcn_readfirstlane(n);
    const int gs = __builtin_amdgcn_readfirstlane(gi);
    const int* ki = knn + ns * KNN;
    int idxs[KNN];
    #pragma unroll
    for (int j = 0; j < KNN; j++) idxs[j] = ki[j];

    ushort4 vr[KNN];
    #pragma unroll
    for (int j = 0; j < KNN; j++)
        vr[j] = *(const ushort4*)(Vt + (size_t)(base + idxs[j]) * CDIM + lane * 4);
    __builtin_amdgcn_sched_barrier(0);

    // wave-uniform prob reads -> scalar loads
    const float* pp = probs + (size_t)gs * KNN;
    float p[KNN];
    #pragma unroll
    for (int j = 0; j < KNN; j++) p[j] = pp[j];

    const u16x4 qh = __builtin_nontemporal_load(
        (const u16x4*)(Qb + (size_t)gi * CDIM + lane * 4));
    f4 q;
    q[0] = bf2f(qh[0]); q[1] = bf2f(qh[1]); q[2] = bf2f(qh[2]); q[3] = bf2f(qh[3]);

    f4 o = (f4){0.f, 0.f, 0.f, 0.f};
    #pragma unroll
    for (int j = 0; j < KNN; j++) {
        o[0] += p[j] * bf2f(vr[j].x); o[1] += p[j] * bf2f(vr[j].y);
        o[2] += p[j] * bf2f(vr[j].z); o[3] += p[j] * bf2f(vr[j].w);
    }

    f4 x = o + q;

    float ssum = x[0] + x[1] + x[2] + x[3];
    #pragma unroll
    for (int m = 1; m < 64; m <<= 1) ssum += __shfl_xor(ssum, m, 64);
    const float mu = ssum * (1.f / 256.f);

    f4 e;
    e[0] = x[0] - mu; e[1] = x[1] - mu; e[2] = x[2] - mu; e[3] = x[3] - mu;
    float vsum = e[0] * e[0] + e[1] * e[1] + e[2] * e[2] + e[3] * e[3];
    #pragma unroll
    for (int m = 1; m < 64; m <<= 1) vsum += __shfl_xor(vsum, m, 64);
    const float rstd = rsqrtf(vsum * (1.f / 256.f) + 1e-5f);

    const f4 g  = *(const f4*)(ln_g + lane * 4);
    const f4 bb = *(const f4*)(ln_b + lane * 4);
    f4 outv;
    outv[0] = e[0] * rstd * g[0] + bb[0];
    outv[1] = e[1] * rstd * g[1] + bb[1];
    outv[2] = e[2] * rstd * g[2] + bb[2];
    outv[3] = e[3] * rstd * g[3] + bb[3];
    __builtin_nontemporal_store(outv, (f4*)(Out + (size_t)gi * CDIM + lane * 4));
}

extern "C" void kernel_launch(void* const* d_in, const int* in_sizes, int n_in,
                              void* d_out, int out_size, void* d_ws, size_t ws_size,
                              hipStream_t stream)
{
    const float* q_feat  = (const float*)d_in[0];
    const float* kv_feat = (const float*)d_in[1];
    const int*   knn     = (const int*)d_in[2];
    const float* sens    = (const float*)d_in[3];
    const float* Wq_w    = (const float*)d_in[4];
    const float* Wq_b    = (const float*)d_in[5];
    const float* Wk_w    = (const float*)d_in[6];
    const float* Wk_b    = (const float*)d_in[7];
    const float* Wv_w    = (const float*)d_in[8];
    const float* Wv_b    = (const float*)d_in[9];
    const float* ln_g    = (const float*)d_in[10];
    const float* ln_b    = (const float*)d_in[11];

    const int Npts = in_sizes[3];              // N = 50000
    const int M    = in_sizes[0] / CDIM;       // B*N = 100000
    const int ngroups = (M + 255) / 256;       // 391 groups of 256 rows

    ushort* Qb  = (ushort*)d_ws;               // [M][256] bf16 (51.2 MB)
    ushort* Kt  = Qb + (size_t)M * CDIM;       // [M][256] bf16 (51.2 MB)
    ushort* Vt  = Kt + (size_t)M * CDIM;       // [M][256] bf16 (51.2 MB)
    float* probs = (float*)(Vt + (size_t)M * CDIM);  // [M][16] f32 (6.4 MB)

    proj_kv<<<4 * NCKV, 1024, 0, stream>>>(kv_feat, Wk_w, Wv_w, Wk_b, Wv_b,
                                           sens, Kt, Vt, M, Npts, 4 * NCKV, ngroups);
    proj_q<<<4 * NCQ, 1024, 0, stream>>>(q_feat, Wq_w, Wq_b, Qb,
                                         M, 4 * NCQ, ngroups);

    const int nblk = (2 * Npts + 3) / 4;
    attn_score<<<nblk, 256, 0, stream>>>(Qb, Kt, knn, probs, Npts);
    attn_pv<<<nblk, 256, 0, stream>>>(Qb, Vt, knn, probs, (float*)d_out,
                                      ln_g, ln_b, Npts);
}

// Round 17
// 384.658 us; speedup vs baseline: 1.0077x; 1.0077x over previous
//
#include <hip/hip_runtime.h>
#include <hip/hip_bf16.h>
#include <cstdint>

#define CDIM 256
#define KNN  16
#define NCQ  128    // Q chunks:  grid 4*128 = 512 blocks (2/CU, 32 waves/CU)
#define NCKV 64     // KV chunks: grid 4*64  = 256 blocks (1/CU, 16 waves/CU)

typedef __attribute__((ext_vector_type(8))) __bf16 bf16x8;
typedef __attribute__((ext_vector_type(4))) float  f4;
typedef __attribute__((ext_vector_type(4))) unsigned short u16x4;

__device__ inline ushort f2bf(float f) {
    __bf16 b = (__bf16)f;
    return __builtin_bit_cast(ushort, b);
}
__device__ inline float bf2f(ushort h) {
    return __builtin_bit_cast(float, (unsigned int)h << 16);
}
__device__ inline bf16x8 cvt8(f4 a, f4 b) {
    bf16x8 r;
    r[0] = (__bf16)a[0]; r[1] = (__bf16)a[1]; r[2] = (__bf16)a[2]; r[3] = (__bf16)a[3];
    r[4] = (__bf16)b[0]; r[5] = (__bf16)b[1]; r[6] = (__bf16)b[2]; r[7] = (__bf16)b[3];
    return r;
}
__device__ inline ushort4 packbf(f4 v) {
    ushort4 h;
    h.x = f2bf(v[0]); h.y = f2bf(v[1]); h.z = f2bf(v[2]); h.w = f2bf(v[3]);
    return h;
}

// stage a 64-row x 256-col f32 weight slice -> bf16 LDS, XOR-swizzled.
__device__ inline void stage_w(const float* Wm, int wbase, ushort* dst, int tid) {
    #pragma unroll
    for (int i = 0; i < 4; i++) {
        int idx = i * 1024 + tid;
        int row = idx >> 6, c4 = idx & 63;
        float4 v = *(const float4*)(Wm + (size_t)(wbase + row) * CDIM + c4 * 4);
        ushort4 h;
        h.x = f2bf(v.x); h.y = f2bf(v.y); h.z = f2bf(v.z); h.w = f2bf(v.w);
        *(ushort4*)((char*)dst + row * 512 + ((c4 * 8) ^ ((row & 7) << 4))) = h;
    }
}

// Q projection: 16-wave blocks, one 32 KB Wq slice, 2 blocks/CU (r12-proven).
__global__ __launch_bounds__(1024, 4)
void proj_q(const float* __restrict__ qf, const float* __restrict__ Wq,
            const float* __restrict__ bq, ushort* __restrict__ Qout,
            int M, int nwg, int ngroups)
{
    __shared__ ushort Wlds[64 * CDIM];   // 32 KB

    const int orig = blockIdx.x;
    const int xcd = orig & 7, lin = orig >> 3;
    const int wgid = xcd * (nwg >> 3) + lin;       // nwg % 8 == 0
    const int chunk = wgid >> 2, ws = wgid & 3;

    const int tid  = threadIdx.x;
    const int lane = tid & 63;
    const int wid  = tid >> 6;                     // 0..15
    const int l15  = lane & 15, l4 = lane >> 4;
    const int wbase = ws * 64;

    stage_w(Wq, wbase, Wlds, tid);
    __syncthreads();

    f4 biasf[4];
    #pragma unroll
    for (int mi = 0; mi < 4; mi++)
        biasf[mi] = *(const f4*)(bq + wbase + mi * 16 + l4 * 4);

    for (int g = chunk; g < ngroups; g += NCQ) {
        const int m0 = g * 256 + wid * 16;
        if (m0 >= M) continue;                     // M % 16 == 0
        const float* fp = qf + (size_t)m0 * CDIM + (size_t)l15 * CDIM + l4 * 8;

        f4 rawA[8], rawB[8];
        #pragma unroll
        for (int ks = 0; ks < 8; ks++) {
            rawA[ks] = *(const f4*)(fp + ks * 32);
            rawB[ks] = *(const f4*)(fp + ks * 32 + 4);
        }
        __builtin_amdgcn_sched_barrier(0);

        f4 acc[4];
        #pragma unroll
        for (int mi = 0; mi < 4; mi++) acc[mi] = (f4){0.f, 0.f, 0.f, 0.f};
        #pragma unroll
        for (int ks = 0; ks < 8; ks++) {
            const bf16x8 af = cvt8(rawA[ks], rawB[ks]);
            #pragma unroll
            for (int mi = 0; mi < 4; mi++) {
                const int r = mi * 16 + l15;
                const bf16x8 wfr = *(const bf16x8*)((const char*)Wlds + r * 512
                                      + ((ks * 64 + l4 * 16) ^ ((r & 7) << 4)));
                acc[mi] = __builtin_amdgcn_mfma_f32_16x16x32_bf16(wfr, af, acc[mi], 0, 0, 0);
            }
        }

        const int m = m0 + l15;
        #pragma unroll
        for (int mi = 0; mi < 4; mi++) {
            const int wr0 = wbase + mi * 16 + l4 * 4;
            *(ushort4*)(Qout + (size_t)m * CDIM + wr0) = packbf(acc[mi] + biasf[mi]);
        }
    }
}

// K+V projection: 16-wave blocks, dual 64 KB Wk/Wv slices. Stores into the
// interleaved [K 512B | V 512B] record per point (r12's measured-best store
// shape: both stores land in one DRAM page; separate arrays cost ~30us).
__global__ __launch_bounds__(1024, 4)
void proj_kv(const float* __restrict__ kvf,
             const float* __restrict__ Wk, const float* __restrict__ Wv,
             const float* __restrict__ bk, const float* __restrict__ bv,
             const float* __restrict__ sens, ushort* __restrict__ KVout,
             int M, int Npts, int nwg, int ngroups)
{
    __shared__ ushort Wlds[2][64 * CDIM];   // 64 KB

    const int orig = blockIdx.x;
    const int xcd = orig & 7, lin = orig >> 3;
    const int wgid = xcd * (nwg >> 3) + lin;
    const int chunk = wgid >> 2, ws = wgid & 3;

    const int tid  = threadIdx.x;
    const int lane = tid & 63;
    const int wid  = tid >> 6;
    const int l15  = lane & 15, l4 = lane >> 4;
    const int wbase = ws * 64;

    stage_w(Wk, wbase, &Wlds[0][0], tid);
    stage_w(Wv, wbase, &Wlds[1][0], tid);
    __syncthreads();

    f4 biasK[4], biasV[4];
    #pragma unroll
    for (int mi = 0; mi < 4; mi++) {
        biasK[mi] = *(const f4*)(bk + wbase + mi * 16 + l4 * 4);
        biasV[mi] = *(const f4*)(bv + wbase + mi * 16 + l4 * 4);
    }

    for (int g = chunk; g < ngroups; g += NCKV) {
        const int m0 = g * 256 + wid * 16;
        if (m0 >= M) continue;
        const float* fp = kvf + (size_t)m0 * CDIM + (size_t)l15 * CDIM + l4 * 8;

        f4 rawA[8], rawB[8];
        #pragma unroll
        for (int ks = 0; ks < 8; ks++) {
            rawA[ks] = *(const f4*)(fp + ks * 32);
            rawB[ks] = *(const f4*)(fp + ks * 32 + 4);
        }
        __builtin_amdgcn_sched_barrier(0);

        f4 accK[4], accV[4];
        #pragma unroll
        for (int mi = 0; mi < 4; mi++) {
            accK[mi] = (f4){0.f, 0.f, 0.f, 0.f};
            accV[mi] = (f4){0.f, 0.f, 0.f, 0.f};
        }
        #pragma unroll
        for (int ks = 0; ks < 8; ks++) {
            const bf16x8 af = cvt8(rawA[ks], rawB[ks]);
            #pragma unroll
            for (int mi = 0; mi < 4; mi++) {
                const int r = mi * 16 + l15;
                const int cb = (ks * 64 + l4 * 16) ^ ((r & 7) << 4);
                const bf16x8 wk = *(const bf16x8*)((const char*)&Wlds[0][0] + r * 512 + cb);
                accK[mi] = __builtin_amdgcn_mfma_f32_16x16x32_bf16(wk, af, accK[mi], 0, 0, 0);
                const bf16x8 wv = *(const bf16x8*)((const char*)&Wlds[1][0] + r * 512 + cb);
                accV[mi] = __builtin_amdgcn_mfma_f32_16x16x32_bf16(wv, af, accV[mi], 0, 0, 0);
            }
        }

        const int m = m0 + l15;
        const int nidx = m >= Npts ? m - Npts : m;
        const float sw = sens[nidx];
        #pragma unroll
        for (int mi = 0; mi < 4; mi++) {
            const int wr0 = wbase + mi * 16 + l4 * 4;
            *(ushort4*)(KVout + (size_t)m * 512 + wr0)       = packbf((accK[mi] + biasK[mi]) * sw);
            *(ushort4*)(KVout + (size_t)m * 512 + 256 + wr0) = packbf((accV[mi] + biasV[mi]) * sw);
        }
    }
}

// Phase A: per point gather 16 K halves (record + lane*4), dot, softmax.
__global__ __launch_bounds__(256, 4)
void attn_score(const ushort* __restrict__ Qb, const ushort* __restrict__ KV,
                const int* __restrict__ knn, float* __restrict__ probs, int Npts)
{
    const int gi = blockIdx.x * 4 + (threadIdx.x >> 6);   // [0, 2*Npts)
    const int lane = threadIdx.x & 63;
    const int base = gi >= Npts ? Npts : 0;
    const int n    = gi - base;
    if (n >= Npts) return;

    const u16x4 qh = __builtin_nontemporal_load(
        (const u16x4*)(Qb + (size_t)gi * CDIM + lane * 4));

    const int ns = __builtin_amdgcn_readfirstlane(n);
    const int* ki = knn + ns * KNN;
    int idxs[KNN];
    #pragma unroll
    for (int j = 0; j < KNN; j++) idxs[j] = ki[j];

    ushort4 kr[KNN];
    #pragma unroll
    for (int j = 0; j < KNN; j++)
        kr[j] = *(const ushort4*)(KV + (size_t)(base + idxs[j]) * 512 + lane * 4);
    __builtin_amdgcn_sched_barrier(0);

    f4 q;
    q[0] = bf2f(qh[0]); q[1] = bf2f(qh[1]); q[2] = bf2f(qh[2]); q[3] = bf2f(qh[3]);

    float d[KNN];
    #pragma unroll
    for (int j = 0; j < KNN; j++)
        d[j] = q[0] * bf2f(kr[j].x) + q[1] * bf2f(kr[j].y)
             + q[2] * bf2f(kr[j].z) + q[3] * bf2f(kr[j].w);

    #pragma unroll
    for (int m = 1; m < 64; m <<= 1) {
        #pragma unroll
        for (int j = 0; j < KNN; j++) d[j] += __shfl_xor(d[j], m, 64);
    }

    float mx = -1e30f;
    #pragma unroll
    for (int j = 0; j < KNN; j++) { d[j] *= 0.0625f; mx = fmaxf(mx, d[j]); }
    float s = 0.f;
    #pragma unroll
    for (int j = 0; j < KNN; j++) { d[j] = __expf(d[j] - mx); s += d[j]; }
    const float inv = 1.f / s;

    if (lane == 0) {
        float* pp = probs + (size_t)gi * KNN;
        __builtin_nontemporal_store(
            (f4){d[0] * inv, d[1] * inv, d[2] * inv, d[3] * inv}, (f4*)pp);
        __builtin_nontemporal_store(
            (f4){d[4] * inv, d[5] * inv, d[6] * inv, d[7] * inv}, (f4*)(pp + 4));
        __builtin_nontemporal_store(
            (f4){d[8] * inv, d[9] * inv, d[10] * inv, d[11] * inv}, (f4*)(pp + 8));
        __builtin_nontemporal_store(
            (f4){d[12] * inv, d[13] * inv, d[14] * inv, d[15] * inv}, (f4*)(pp + 12));
    }
}

// Phase B: per point gather 16 V halves (record + 256 + lane*4), weighted
// sum, residual + LayerNorm.
__global__ __launch_bounds__(256, 4)
void attn_pv(const ushort* __restrict__ Qb, const ushort* __restrict__ KV,
             const int* __restrict__ knn, const float* __restrict__ probs,
             float* __restrict__ Out,
             const float* __restrict__ ln_g, const float* __restrict__ ln_b,
             int Npts)
{
    const int gi = blockIdx.x * 4 + (threadIdx.x >> 6);
    const int lane = threadIdx.x & 63;
    const int base = gi >= Npts ? Npts : 0;
    const int n    = gi - base;
    if (n >= Npts) return;

    const int ns = __builtin_amdgcn_readfirstlane(n);
    const int gs = __builtin_amdgcn_readfirstlane(gi);
    const int* ki = knn + ns * KNN;
    int idxs[KNN];
    #pragma unroll
    for (int j = 0; j < KNN; j++) idxs[j] = ki[j];

    ushort4 vr[KNN];
    #pragma unroll
    for (int j = 0; j < KNN; j++)
        vr[j] = *(const ushort4*)(KV + (size_t)(base + idxs[j]) * 512 + 256 + lane * 4);
    __builtin_amdgcn_sched_barrier(0);

    // wave-uniform prob reads -> scalar loads
    const float* pp = probs + (size_t)gs * KNN;
    float p[KNN];
    #pragma unroll
    for (int j = 0; j < KNN; j++) p[j] = pp[j];

    const u16x4 qh = __builtin_nontemporal_load(
        (const u16x4*)(Qb + (size_t)gi * CDIM + lane * 4));
    f4 q;
    q[0] = bf2f(qh[0]); q[1] = bf2f(qh[1]); q[2] = bf2f(qh[2]); q[3] = bf2f(qh[3]);

    f4 o = (f4){0.f, 0.f, 0.f, 0.f};
    #pragma unroll
    for (int j = 0; j < KNN; j++) {
        o[0] += p[j] * bf2f(vr[j].x); o[1] += p[j] * bf2f(vr[j].y);
        o[2] += p[j] * bf2f(vr[j].z); o[3] += p[j] * bf2f(vr[j].w);
    }

    f4 x = o + q;

    float ssum = x[0] + x[1] + x[2] + x[3];
    #pragma unroll
    for (int m = 1; m < 64; m <<= 1) ssum += __shfl_xor(ssum, m, 64);
    const float mu = ssum * (1.f / 256.f);

    f4 e;
    e[0] = x[0] - mu; e[1] = x[1] - mu; e[2] = x[2] - mu; e[3] = x[3] - mu;
    float vsum = e[0] * e[0] + e[1] * e[1] + e[2] * e[2] + e[3] * e[3];
    #pragma unroll
    for (int m = 1; m < 64; m <<= 1) vsum += __shfl_xor(vsum, m, 64);
    const float rstd = rsqrtf(vsum * (1.f / 256.f) + 1e-5f);

    const f4 g  = *(const f4*)(ln_g + lane * 4);
    const f4 bb = *(const f4*)(ln_b + lane * 4);
    f4 outv;
    outv[0] = e[0] * rstd * g[0] + bb[0];
    outv[1] = e[1] * rstd * g[1] + bb[1];
    outv[2] = e[2] * rstd * g[2] + bb[2];
    outv[3] = e[3] * rstd * g[3] + bb[3];
    __builtin_nontemporal_store(outv, (f4*)(Out + (size_t)gi * CDIM + lane * 4));
}

extern "C" void kernel_launch(void* const* d_in, const int* in_sizes, int n_in,
                              void* d_out, int out_size, void* d_ws, size_t ws_size,
                              hipStream_t stream)
{
    const float* q_feat  = (const float*)d_in[0];
    const float* kv_feat = (const float*)d_in[1];
    const int*   knn     = (const int*)d_in[2];
    const float* sens    = (const float*)d_in[3];
    const float* Wq_w    = (const float*)d_in[4];
    const float* Wq_b    = (const float*)d_in[5];
    const float* Wk_w    = (const float*)d_in[6];
    const float* Wk_b    = (const float*)d_in[7];
    const float* Wv_w    = (const float*)d_in[8];
    const float* Wv_b    = (const float*)d_in[9];
    const float* ln_g    = (const float*)d_in[10];
    const float* ln_b    = (const float*)d_in[11];

    const int Npts = in_sizes[3];              // N = 50000
    const int M    = in_sizes[0] / CDIM;       // B*N = 100000
    const int ngroups = (M + 255) / 256;       // 391 groups of 256 rows

    ushort* Qb   = (ushort*)d_ws;              // [M][256] bf16   (51.2 MB)
    ushort* KVtb = Qb + (size_t)M * CDIM;      // [M] 1KB records (102.4 MB)
    float* probs = (float*)(KVtb + (size_t)M * 512);  // [M][16] f32 (6.4 MB)

    proj_kv<<<4 * NCKV, 1024, 0, stream>>>(kv_feat, Wk_w, Wv_w, Wk_b, Wv_b,
                                           sens, KVtb, M, Npts, 4 * NCKV, ngroups);
    proj_q<<<4 * NCQ, 1024, 0, stream>>>(q_feat, Wq_w, Wq_b, Qb,
                                         M, 4 * NCQ, ngroups);

    const int nblk = (2 * Npts + 3) / 4;
    attn_score<<<nblk, 256, 0, stream>>>(Qb, KVtb, knn, probs, Npts);
    attn_pv<<<nblk, 256, 0, stream>>>(Qb, KVtb, knn, probs, (float*)d_out,
                                      ln_g, ln_b, Npts);
}